// Round 1
// 1294.837 us; speedup vs baseline: 1.1555x; 1.1555x over previous
//
#include <hip/hip_runtime.h>
#include <hip/hip_bf16.h>
#include <cstdint>

// GMMSA: proj(1x1) -> GroupNorm(2) -> 3x windowed self-attn (q==k) -> fuse(1x1)
// Identity used: attn_g rows == attn rows at gidx  =>  global-token branch is a
// no-op; outputs are exactly (fuse(concat(sw_i * attn_i @ v_i)), attn_0..2).
// I/O dtype: float32 (per reference). Internal xp/yf staged as bf16 in d_ws.

typedef __hip_bfloat16 bf16;
typedef __hip_bfloat162 bf162;

#define IMG 192
#define PIX (IMG*IMG)   // 36864
#define CIN 180
#define CMID 360

__device__ __forceinline__ float b2f(bf16 v){ return __bfloat162float(v); }
__device__ __forceinline__ bf16 f2b(float v){ return __float2bfloat16(v); }

__device__ __forceinline__ void ld2(const float* p, float& a, float& b){
    float2 v = *reinterpret_cast<const float2*>(p); a = v.x; b = v.y;
}
__device__ __forceinline__ void ld2(const bf16* p, float& a, float& b){
    uint32_t u = *reinterpret_cast<const uint32_t*>(p);
    a = __uint_as_float(u << 16);          // p[0] (low half)
    b = __uint_as_float(u & 0xffff0000u);  // p[1] (high half)
}
__device__ __forceinline__ void st2(float* p, float a, float b){
    *reinterpret_cast<float2*>(p) = make_float2(a, b);
}
__device__ __forceinline__ void st2(bf16* p, float a, float b){
    bf162 w; w.x = f2b(a); w.y = f2b(b);
    *reinterpret_cast<bf162*>(p) = w;
}

// ---- 1x1-conv GEMM: Y[b,o,p] = sum_c W[o,c] X[b,c,p] + B[o]  (+GN stats) ----
// Latency-bound fix vs v1: OT=30 (60 FMA per X load), 4-deep c-pipeline
// (4 float2 loads in flight per wave), float4 scalar weight loads, and an
// XCD-locality swizzle so the M/OT blocks sharing a pixel tile land on the
// same XCD's L2 (gridDim.x must be divisible by 8; otile varies fastest).
template<int OT, bool STATS, typename XT, typename YT>
__global__ __launch_bounds__(256, 4) void k_gemm(
    const float* __restrict__ W, const float* __restrict__ Bv,
    const XT* __restrict__ X, YT* __restrict__ Y,
    float* __restrict__ stats, int M, int K)
{
    __shared__ float red[4][4];
    const int tid = threadIdx.x;
    const int bz  = blockIdx.z;

    // XCD swizzle: consecutive hardware wg ids round-robin XCDs (id % 8).
    // Remap so each XCD owns a contiguous chunk of work, ordered otile-fastest:
    // the nbx blocks of one pixel tile are consecutive -> same XCD -> L2 reuse.
    const int nbx   = M / OT;
    const int chunk = gridDim.x >> 3;          // gridDim.x % 8 == 0
    const int wk    = (blockIdx.x & 7) * chunk + (blockIdx.x >> 3);
    const int ob    = wk % nbx;
    const int pt    = wk / nbx;

    const int o0 = ob * OT;
    const int p  = pt * 512 + tid * 2;

    float acc0[OT], acc1[OT];
#pragma unroll
    for (int j=0;j<OT;j++){acc0[j]=0.f;acc1[j]=0.f;}
    const XT* Xp = X + (size_t)bz*K*PIX + p;
    const float* Wp = W + (size_t)o0*K;

    // 4-deep rolling pipeline over c
    float xc[4][2], xn[4][2];
#pragma unroll
    for (int u=0;u<4;u++) ld2(Xp + (size_t)u*PIX, xc[u][0], xc[u][1]);

#pragma unroll 1
    for (int c = 0; c < K; c += 4) {
        if (c + 4 < K) {
#pragma unroll
            for (int u=0;u<4;u++)
                ld2(Xp + (size_t)(c+4+u)*PIX, xn[u][0], xn[u][1]);
        }
#pragma unroll
        for (int j=0;j<OT;j++){
            // uniform address -> s_load_dwordx4 (scalar cache)
            float4 wv = *reinterpret_cast<const float4*>(Wp + (size_t)j*K + c);
            acc0[j] = fmaf(xc[0][0], wv.x, acc0[j]);
            acc1[j] = fmaf(xc[0][1], wv.x, acc1[j]);
            acc0[j] = fmaf(xc[1][0], wv.y, acc0[j]);
            acc1[j] = fmaf(xc[1][1], wv.y, acc1[j]);
            acc0[j] = fmaf(xc[2][0], wv.z, acc0[j]);
            acc1[j] = fmaf(xc[2][1], wv.z, acc1[j]);
            acc0[j] = fmaf(xc[3][0], wv.w, acc0[j]);
            acc1[j] = fmaf(xc[3][1], wv.w, acc1[j]);
        }
#pragma unroll
        for (int u=0;u<4;u++){ xc[u][0]=xn[u][0]; xc[u][1]=xn[u][1]; }
    }

    float s0=0.f,s1=0.f,q0=0.f,q1=0.f;
#pragma unroll
    for (int j=0;j<OT;j++){
        int o = o0 + j;
        float bb = Bv[o];
        float v0 = acc0[j] + bb, v1 = acc1[j] + bb;
        st2(Y + (size_t)(bz*M + o)*PIX + p, v0, v1);
        if (STATS) {
            if (o < 180){ s0 += v0+v1; q0 += fmaf(v0,v0,v1*v1); }
            else        { s1 += v0+v1; q1 += fmaf(v0,v0,v1*v1); }
        }
    }
    if (STATS) {
#pragma unroll
        for (int off=32; off>0; off>>=1){
            s0 += __shfl_down(s0, off); s1 += __shfl_down(s1, off);
            q0 += __shfl_down(q0, off); q1 += __shfl_down(q1, off);
        }
        int wv = tid>>6, ln = tid&63;
        if (ln==0){ red[0][wv]=s0; red[1][wv]=s1; red[2][wv]=q0; red[3][wv]=q1; }
        __syncthreads();
        if (tid==0){
            float r0=red[0][0]+red[0][1]+red[0][2]+red[0][3];
            float r1=red[1][0]+red[1][1]+red[1][2]+red[1][3];
            float r2=red[2][0]+red[2][1]+red[2][2]+red[2][3];
            float r3=red[3][0]+red[3][1]+red[3][2]+red[3][3];
            atomicAdd(&stats[(bz*2+0)*2+0], r0);
            atomicAdd(&stats[(bz*2+1)*2+0], r1);
            atomicAdd(&stats[(bz*2+0)*2+1], r2);
            atomicAdd(&stats[(bz*2+1)*2+1], r3);
        }
    }
}

// ---- finalize GN stats: stats[0..7]=sum/sumsq per (b,g); writes mu/rsig at [8..15] ----
__global__ void k_stats(float* stats)
{
    int i = threadIdx.x;
    if (i < 4) {
        const float n = 180.0f*36864.0f;
        float mu  = stats[i*2] / n;
        float var = stats[i*2+1]/n - mu*mu;
        stats[8 + i*2]     = mu;
        stats[8 + i*2 + 1] = rsqrtf(var + 1e-5f);
    }
}

// ---- windowed self-attention (q==k), one (window, head, row-split) per block ----
// Sm stored transposed [s][t_local] with stride TR+1 (odd) -> conflict-free phases.
template<int WS, int HE, int CHN, int SI, int SPLIT, int RROW, int NSC>
__global__ __launch_bounds__(256) void k_attn(
    const bf16* __restrict__ xp, const float* __restrict__ musig,
    const float* __restrict__ gamma, const float* __restrict__ beta,
    const float* __restrict__ swt,
    float* __restrict__ atn, bf16* __restrict__ yf)
{
    constexpr int T = WS*WS;
    constexpr int NWIN = IMG/WS;
    constexpr int TR = T/SPLIT;       // rows of S this block owns
    constexpr int PP = TR/RROW;
    constexpr int SLEN = T/NSC;
    constexpr int ST = TR + 1;        // odd stride
    __shared__ float qs[T*CHN];
    __shared__ float vs[T*CHN];
    __shared__ float Sm[T*ST];        // [s][tl]
    __shared__ float rinv[TR];

    const int tid = threadIdx.x;
    const int wid = blockIdx.x;
    const int head = blockIdx.y;
    const int tb = blockIdx.z * TR;
    const int bi = wid / (NWIN*NWIN);
    const int r2 = wid - bi*(NWIN*NWIN);
    const int wy = r2 / NWIN;
    const int wx = r2 - wy*NWIN;

    // load Q/V with GroupNorm applied; rolls folded into source-pixel math
    for (int idx = tid; idx < 2*T*CHN; idx += 256) {
        int qv = idx / (T*CHN);
        int rem = idx - qv*(T*CHN);
        int t = rem / CHN;
        int c = rem - t*CHN;
        int chan = SI*120 + qv*60 + c*HE + head;
        int r = t / WS, cc = t - r*WS;
        int sh = wy*WS + r - WS/2;  if (sh < 0) sh += IMG;
        int sw = wx*WS + cc + WS/2; if (sw >= IMG) sw -= IMG;
        float val = b2f(xp[((size_t)(bi*CMID + chan)*IMG + sh)*IMG + sw]);
        int g = (chan >= 180) ? 1 : 0;
        float mu = musig[(bi*2+g)*2+0];
        float rs = musig[(bi*2+g)*2+1];
        float xn = fmaf((val - mu)*rs, gamma[chan], beta[chan]);
        if (qv) vs[t*CHN+c] = xn; else qs[t*CHN+c] = xn;
    }
    __syncthreads();

    // S[t,s] = (q[t].q[s]) / HE  for t in [tb, tb+TR); q[s] reads are wave-uniform
    constexpr float invHE = 1.0f/(float)HE;
    for (int item = tid; item < PP*NSC; item += 256) {
        int sc = item / PP;
        int p2 = item - sc*PP;
        int tl0 = p2*RROW;
        float qreg[RROW][CHN];
#pragma unroll
        for (int rr=0; rr<RROW; ++rr)
#pragma unroll
            for (int c=0;c<CHN;c++)
                qreg[rr][c] = qs[(tb + tl0 + rr)*CHN + c];
        for (int j=0;j<SLEN;++j) {
            int s = sc*SLEN + j;
            float d[RROW];
#pragma unroll
            for (int rr=0;rr<RROW;++rr) d[rr]=0.f;
#pragma unroll
            for (int c=0;c<CHN;c++){
                float qc = qs[s*CHN + c];
#pragma unroll
                for (int rr=0;rr<RROW;++rr)
                    d[rr] = fmaf(qreg[rr][c], qc, d[rr]);
            }
#pragma unroll
            for (int rr=0;rr<RROW;++rr)
                Sm[s*ST + tl0 + rr] = d[rr]*invHE;
        }
    }
    __syncthreads();

    // per-row softmax (exp stored in place, 1/sum in rinv)
    for (int tl = tid; tl < TR; tl += 256) {
        float mx = -1e30f;
        for (int s=0;s<T;s++) mx = fmaxf(mx, Sm[s*ST + tl]);
        float sum = 0.f;
        for (int s=0;s<T;s++){
            float e = __expf(Sm[s*ST + tl] - mx);
            Sm[s*ST + tl] = e;
            sum += e;
        }
        rinv[tl] = 1.0f/sum;
    }
    __syncthreads();

    // write P (== out_attn, global branch is identity) — coalesced float2
    {
        size_t abase = ((size_t)wid*HE + head)*(size_t)(T*T) + (size_t)tb*T;
        for (int e2 = tid; e2 < TR*T/2; e2 += 256) {
            int e = e2*2;
            int tl = e / T;
            int s = e - tl*T;
            float ri = rinv[tl];
            st2(atn + abase + e, Sm[s*ST + tl]*ri, Sm[(s+1)*ST + tl]*ri);
        }
    }

    // out[t,c] = (sum_s e[t,s] v[s,c]) * rinv[t] * scale_w -> scatter to y_fused
    float swf = swt[SI];
    for (int item = tid; item < (TR/2)*CHN; item += 256) {
        int tp = item / CHN;
        int c = item - tp*CHN;
        int tl0 = tp*2;
        float a0=0.f, a1=0.f;
        for (int s=0;s<T;s++){
            float vv = vs[s*CHN + c];
            a0 = fmaf(Sm[s*ST + tl0],   vv, a0);
            a1 = fmaf(Sm[s*ST + tl0+1], vv, a1);
        }
        int yc = SI*60 + c*HE + head;
#pragma unroll
        for (int k2=0;k2<2;k2++){
            int tl = tl0 + k2;
            int t = tb + tl;
            float ov = (k2 ? a1 : a0) * rinv[tl] * swf;
            int r = t / WS, cc = t - r*WS;
            int sh = wy*WS + r - WS/2;  if (sh < 0) sh += IMG;
            int sw = wx*WS + cc + WS/2; if (sw >= IMG) sw -= IMG;
            yf[((size_t)(bi*CIN + yc)*IMG + sh)*IMG + sw] = f2b(ov);
        }
    }
}

extern "C" void kernel_launch(void* const* d_in, const int* in_sizes, int n_in,
                              void* d_out, int out_size, void* d_ws, size_t ws_size,
                              hipStream_t stream)
{
    (void)in_sizes; (void)n_in; (void)out_size; (void)ws_size;
    const float* x   = (const float*)d_in[0];
    const float* pw  = (const float*)d_in[1];
    const float* pb  = (const float*)d_in[2];
    const float* gg  = (const float*)d_in[3];
    const float* gb  = (const float*)d_in[4];
    // d_in[5] token_scores: unused (global-token branch is mathematically identity)
    const float* swt = (const float*)d_in[6];
    const float* fw  = (const float*)d_in[7];
    const float* fb  = (const float*)d_in[8];

    float* out  = (float*)d_out;
    float* atn0 = out + 13271040;            // (4608,2,16,16)
    float* atn1 = out + 15630336;            // (1152,4,64,64)
    float* atn2 = out + 34504704;            // (512,6,144,144)

    char* ws = (char*)d_ws;
    bf16*  xp    = (bf16*)ws;                               // 26,542,080 elems
    bf16*  yf    = (bf16*)(ws + 53084160);                  // 13,271,040 elems
    float* stats = (float*)(ws + 53084160 + 26542080);      // 16 floats

    hipMemsetAsync(stats, 0, 64, stream);
    // proj GEMM + GN partial sums: OT=30 -> nbx=12, 72 pixel tiles, grid.x=864 (div by 8)
    k_gemm<30,true,float,bf16><<<dim3(864,1,2), 256, 0, stream>>>(pw, pb, x, xp, stats, 360, 180);
    k_stats<<<1, 64, 0, stream>>>(stats);
    // attention scales: <WS,HE,CHN,SI,SPLIT,RROW,NSC>
    k_attn<4, 2, 30, 0, 1, 1, 16><<<dim3(4608,2,1), 256, 0, stream>>>(xp, stats+8, gg, gb, swt, atn0, yf);
    k_attn<8, 4, 15, 1, 1, 2, 8 ><<<dim3(1152,4,1), 256, 0, stream>>>(xp, stats+8, gg, gb, swt, atn1, yf);
    k_attn<12,6, 10, 2, 2, 2, 8 ><<<dim3(512, 6,2), 256, 0, stream>>>(xp, stats+8, gg, gb, swt, atn2, yf);
    // fuse GEMM (scale_weights already folded into yf): OT=30 -> nbx=6, grid.x=432 (div by 8)
    k_gemm<30,false,bf16,float><<<dim3(432,1,2), 256, 0, stream>>>(fw, fb, yf, out, nullptr, 180, 180);
}

// Round 2
// 1241.899 us; speedup vs baseline: 1.2047x; 1.0426x over previous
//
#include <hip/hip_runtime.h>
#include <hip/hip_bf16.h>
#include <cstdint>

// GMMSA: proj(1x1) -> GroupNorm(2) -> 3x windowed self-attn (q==k) -> fuse(1x1)
// Identity used: attn_g rows == attn rows at gidx  =>  global-token branch is a
// no-op; outputs are exactly (fuse(concat(sw_i * attn_i @ v_i)), attn_0..2).
// I/O dtype: float32 (per reference). Internal xp/yf staged as bf16 in d_ws.
//
// R2: both 1x1-conv GEMMs moved to MFMA (16x16x32 bf16) with split-precision:
//   proj: Y = Wh*Xh + Wh*Xl + Wl*Xh   (error ~2^-17, below bf16 staging error)
//   fuse: Y = Wh*X  + Wl*X            (X already bf16 exact)

typedef __hip_bfloat16 bf16;
typedef __hip_bfloat162 bf162;
typedef __attribute__((ext_vector_type(8))) __bf16 bf16x8;
typedef __attribute__((ext_vector_type(4))) float f32x4;

#define IMG 192
#define PIX (IMG*IMG)   // 36864
#define CIN 180
#define CMID 360

__device__ __forceinline__ float b2f(bf16 v){ return __bfloat162float(v); }
__device__ __forceinline__ bf16 f2b(float v){ return __float2bfloat16(v); }

__device__ __forceinline__ void st2(float* p, float a, float b){
    *reinterpret_cast<float2*>(p) = make_float2(a, b);
}
__device__ __forceinline__ void st2(bf16* p, float a, float b){
    bf162 w; w.x = f2b(a); w.y = f2b(b);
    *reinterpret_cast<bf162*>(p) = w;
}

// ---- bf16 hi/lo split helpers -------------------------------------------
__device__ __forceinline__ void split2(float x, unsigned short& h, unsigned short& l){
    __bf16 bh = (__bf16)x;
    float fh = (float)bh;
    __bf16 bl = (__bf16)(x - fh);
    h = __builtin_bit_cast(unsigned short, bh);
    l = __builtin_bit_cast(unsigned short, bl);
}

union FragU { unsigned short s[8]; uint32_t u[4]; bf16x8 v; };

__device__ __forceinline__ f32x4 mf(bf16x8 a, bf16x8 b, f32x4 c){
    return __builtin_amdgcn_mfma_f32_16x16x32_bf16(a, b, c, 0, 0, 0);
}

// ---- MFMA 1x1-conv GEMM: Y[b,o,p] = sum_c W[o,c] X[b,c,p] + B[o] (+GN stats)
// Block: 64(M) x 64(N), 4 waves split on M (16 rows each). K=180 padded to 192.
// X staged in LDS as packed bf16 pairs [k2][p], row stride 67 words (~conflict-free).
// A (W rows) preloaded to registers as 6 K-step hi/lo fragments.
template<int MT, int KK, int XSPLIT, bool STATS, typename XT, typename YT>
__global__ __launch_bounds__(256, 3) void k_gemm_mfma(
    const float* __restrict__ W, const float* __restrict__ Bv,
    const XT* __restrict__ X, YT* __restrict__ Y,
    float* __restrict__ stats)
{
    constexpr int KP   = 192;          // padded K (6 MFMA K-steps of 32)
    constexpr int NK2  = KP/2;         // 96 packed k-pair rows
    constexpr int LSTR = 67;           // LDS row stride in words (67 % 32 = 3)
    constexpr int MTILES = (MT + 63)/64;
    __shared__ uint32_t ldsb[XSPLIT*NK2*LSTR];
    __shared__ float red[4][4];

    const int tid = threadIdx.x;
    const int bz  = blockIdx.z;

    // XCD swizzle: group the MTILES blocks sharing an N-tile on one XCD.
    const int chunk = gridDim.x >> 3;            // gridDim.x % 8 == 0
    const int wk    = (blockIdx.x & 7)*chunk + (blockIdx.x >> 3);
    const int mtile = wk % MTILES;
    const int ntile = wk / MTILES;
    const int p0    = ntile*64;

    const int w  = tid >> 6;           // wave id (M sub-tile)
    const int l  = tid & 63;
    const int am = l & 15;             // A row / B col / D col lane index
    const int kg = l >> 4;             // K-group (8 elems) / D row group

    // ---- A preload: rows obase..obase+15, 6 K-steps, hi/lo fragments ----
    const int obase = mtile*64 + w*16;
    int arow = obase + am; if (arow >= MT) arow = MT-1;
    const float* wr = W + (size_t)arow*KK;
    bf16x8 Ah[6], Al[6];
#pragma unroll
    for (int s=0;s<6;s++){
        const int k0 = s*32 + kg*8;
        float wv[8];
        if (k0 + 8 <= KK) {
            float4 a = *reinterpret_cast<const float4*>(wr + k0);
            float4 b = *reinterpret_cast<const float4*>(wr + k0 + 4);
            wv[0]=a.x; wv[1]=a.y; wv[2]=a.z; wv[3]=a.w;
            wv[4]=b.x; wv[5]=b.y; wv[6]=b.z; wv[7]=b.w;
        } else {
#pragma unroll
            for (int j=0;j<8;j++) wv[j] = (k0+j < KK) ? wr[k0+j] : 0.f;
        }
        FragU fh, fl;
#pragma unroll
        for (int j=0;j<8;j++){
            unsigned short hh, ll;
            split2(wv[j], hh, ll);
            fh.s[j] = hh; fl.s[j] = ll;
        }
        Ah[s] = fh.v; Al[s] = fl.v;
    }

    // ---- stage X tile [k2][p] as packed bf16 pairs (hi, and lo if XSPLIT==2)
    for (int idx = tid; idx < NK2*64; idx += 256){
        const int k2 = idx >> 6;
        const int p  = idx & 63;
        uint32_t hw = 0, lw = 0;
        if (2*k2 < KK) {
            const XT* s0 = X + ((size_t)bz*KK + 2*k2)*PIX + p0 + p;
            if constexpr (XSPLIT == 2) {
                float x0 = (float)s0[0], x1 = (float)s0[PIX];
                unsigned short h0,l0,h1,l1;
                split2(x0,h0,l0); split2(x1,h1,l1);
                hw = (uint32_t)h0 | ((uint32_t)h1 << 16);
                lw = (uint32_t)l0 | ((uint32_t)l1 << 16);
            } else {
                const unsigned short* us = reinterpret_cast<const unsigned short*>(s0);
                hw = (uint32_t)us[0] | ((uint32_t)us[PIX] << 16);
            }
        }
        ldsb[k2*LSTR + p] = hw;
        if constexpr (XSPLIT == 2) ldsb[NK2*LSTR + k2*LSTR + p] = lw;
    }
    __syncthreads();

    // ---- MFMA main loop: 6 K-steps x 4 N-subtiles ----
    f32x4 acc[4];
#pragma unroll
    for (int n=0;n<4;n++) acc[n] = (f32x4){0.f,0.f,0.f,0.f};

#pragma unroll
    for (int s=0;s<6;s++){
        const int kw = s*16 + kg*4;    // packed-pair row base for this lane group
#pragma unroll
        for (int n=0;n<4;n++){
            FragU bh;
#pragma unroll
            for (int j2=0;j2<4;j2++)
                bh.u[j2] = ldsb[(kw+j2)*LSTR + n*16 + am];
            if constexpr (XSPLIT == 2) {
                FragU bl;
#pragma unroll
                for (int j2=0;j2<4;j2++)
                    bl.u[j2] = ldsb[NK2*LSTR + (kw+j2)*LSTR + n*16 + am];
                acc[n] = mf(Ah[s], bh.v, acc[n]);
                acc[n] = mf(Ah[s], bl.v, acc[n]);
                acc[n] = mf(Al[s], bh.v, acc[n]);
            } else {
                acc[n] = mf(Ah[s], bh.v, acc[n]);
                acc[n] = mf(Al[s], bh.v, acc[n]);
            }
        }
    }

    // ---- epilogue: bias, store, GN stats ----
    float s0=0.f,s1=0.f,q0=0.f,q1=0.f;
#pragma unroll
    for (int r=0;r<4;r++){
        const int o = obase + kg*4 + r;
        if (o < MT) {
            const float bb = Bv[o];
#pragma unroll
            for (int n=0;n<4;n++){
                float v = acc[n][r] + bb;
                size_t yi = ((size_t)bz*MT + o)*PIX + p0 + n*16 + am;
                if constexpr (sizeof(YT)==2) Y[yi] = f2b(v); else Y[yi] = v;
                if (STATS) {
                    if (o < 180){ s0 += v; q0 += v*v; }
                    else        { s1 += v; q1 += v*v; }
                }
            }
        }
    }
    if (STATS) {
#pragma unroll
        for (int off=32; off>0; off>>=1){
            s0 += __shfl_down(s0, off); s1 += __shfl_down(s1, off);
            q0 += __shfl_down(q0, off); q1 += __shfl_down(q1, off);
        }
        if (l==0){ red[0][w]=s0; red[1][w]=s1; red[2][w]=q0; red[3][w]=q1; }
        __syncthreads();
        if (tid==0){
            float r0=red[0][0]+red[0][1]+red[0][2]+red[0][3];
            float r1=red[1][0]+red[1][1]+red[1][2]+red[1][3];
            float r2=red[2][0]+red[2][1]+red[2][2]+red[2][3];
            float r3=red[3][0]+red[3][1]+red[3][2]+red[3][3];
            atomicAdd(&stats[(bz*2+0)*2+0], r0);
            atomicAdd(&stats[(bz*2+1)*2+0], r1);
            atomicAdd(&stats[(bz*2+0)*2+1], r2);
            atomicAdd(&stats[(bz*2+1)*2+1], r3);
        }
    }
}

// ---- finalize GN stats: stats[0..7]=sum/sumsq per (b,g); writes mu/rsig at [8..15] ----
__global__ void k_stats(float* stats)
{
    int i = threadIdx.x;
    if (i < 4) {
        const float n = 180.0f*36864.0f;
        float mu  = stats[i*2] / n;
        float var = stats[i*2+1]/n - mu*mu;
        stats[8 + i*2]     = mu;
        stats[8 + i*2 + 1] = rsqrtf(var + 1e-5f);
    }
}

// ---- windowed self-attention (q==k), one (window, head, row-split) per block ----
// Sm stored transposed [s][t_local] with stride TR+1 (odd) -> conflict-free phases.
template<int WS, int HE, int CHN, int SI, int SPLIT, int RROW, int NSC>
__global__ __launch_bounds__(256) void k_attn(
    const bf16* __restrict__ xp, const float* __restrict__ musig,
    const float* __restrict__ gamma, const float* __restrict__ beta,
    const float* __restrict__ swt,
    float* __restrict__ atn, bf16* __restrict__ yf)
{
    constexpr int T = WS*WS;
    constexpr int NWIN = IMG/WS;
    constexpr int TR = T/SPLIT;       // rows of S this block owns
    constexpr int PP = TR/RROW;
    constexpr int SLEN = T/NSC;
    constexpr int ST = TR + 1;        // odd stride
    __shared__ float qs[T*CHN];
    __shared__ float vs[T*CHN];
    __shared__ float Sm[T*ST];        // [s][tl]
    __shared__ float rinv[TR];

    const int tid = threadIdx.x;
    const int wid = blockIdx.x;
    const int head = blockIdx.y;
    const int tb = blockIdx.z * TR;
    const int bi = wid / (NWIN*NWIN);
    const int r2 = wid - bi*(NWIN*NWIN);
    const int wy = r2 / NWIN;
    const int wx = r2 - wy*NWIN;

    // load Q/V with GroupNorm applied; rolls folded into source-pixel math
    for (int idx = tid; idx < 2*T*CHN; idx += 256) {
        int qv = idx / (T*CHN);
        int rem = idx - qv*(T*CHN);
        int t = rem / CHN;
        int c = rem - t*CHN;
        int chan = SI*120 + qv*60 + c*HE + head;
        int r = t / WS, cc = t - r*WS;
        int sh = wy*WS + r - WS/2;  if (sh < 0) sh += IMG;
        int sw = wx*WS + cc + WS/2; if (sw >= IMG) sw -= IMG;
        float val = b2f(xp[((size_t)(bi*CMID + chan)*IMG + sh)*IMG + sw]);
        int g = (chan >= 180) ? 1 : 0;
        float mu = musig[(bi*2+g)*2+0];
        float rs = musig[(bi*2+g)*2+1];
        float xn = fmaf((val - mu)*rs, gamma[chan], beta[chan]);
        if (qv) vs[t*CHN+c] = xn; else qs[t*CHN+c] = xn;
    }
    __syncthreads();

    // S[t,s] = (q[t].q[s]) / HE  for t in [tb, tb+TR); q[s] reads are wave-uniform
    constexpr float invHE = 1.0f/(float)HE;
    for (int item = tid; item < PP*NSC; item += 256) {
        int sc = item / PP;
        int p2 = item - sc*PP;
        int tl0 = p2*RROW;
        float qreg[RROW][CHN];
#pragma unroll
        for (int rr=0; rr<RROW; ++rr)
#pragma unroll
            for (int c=0;c<CHN;c++)
                qreg[rr][c] = qs[(tb + tl0 + rr)*CHN + c];
        for (int j=0;j<SLEN;++j) {
            int s = sc*SLEN + j;
            float d[RROW];
#pragma unroll
            for (int rr=0;rr<RROW;++rr) d[rr]=0.f;
#pragma unroll
            for (int c=0;c<CHN;c++){
                float qc = qs[s*CHN + c];
#pragma unroll
                for (int rr=0;rr<RROW;++rr)
                    d[rr] = fmaf(qreg[rr][c], qc, d[rr]);
            }
#pragma unroll
            for (int rr=0;rr<RROW;++rr)
                Sm[s*ST + tl0 + rr] = d[rr]*invHE;
        }
    }
    __syncthreads();

    // per-row softmax (exp stored in place, 1/sum in rinv)
    for (int tl = tid; tl < TR; tl += 256) {
        float mx = -1e30f;
        for (int s=0;s<T;s++) mx = fmaxf(mx, Sm[s*ST + tl]);
        float sum = 0.f;
        for (int s=0;s<T;s++){
            float e = __expf(Sm[s*ST + tl] - mx);
            Sm[s*ST + tl] = e;
            sum += e;
        }
        rinv[tl] = 1.0f/sum;
    }
    __syncthreads();

    // write P (== out_attn, global branch is identity) — coalesced float2
    {
        size_t abase = ((size_t)wid*HE + head)*(size_t)(T*T) + (size_t)tb*T;
        for (int e2 = tid; e2 < TR*T/2; e2 += 256) {
            int e = e2*2;
            int tl = e / T;
            int s = e - tl*T;
            float ri = rinv[tl];
            st2(atn + abase + e, Sm[s*ST + tl]*ri, Sm[(s+1)*ST + tl]*ri);
        }
    }

    // out[t,c] = (sum_s e[t,s] v[s,c]) * rinv[t] * scale_w -> scatter to y_fused
    float swf = swt[SI];
    for (int item = tid; item < (TR/2)*CHN; item += 256) {
        int tp = item / CHN;
        int c = item - tp*CHN;
        int tl0 = tp*2;
        float a0=0.f, a1=0.f;
        for (int s=0;s<T;s++){
            float vv = vs[s*CHN + c];
            a0 = fmaf(Sm[s*ST + tl0],   vv, a0);
            a1 = fmaf(Sm[s*ST + tl0+1], vv, a1);
        }
        int yc = SI*60 + c*HE + head;
#pragma unroll
        for (int k2=0;k2<2;k2++){
            int tl = tl0 + k2;
            int t = tb + tl;
            float ov = (k2 ? a1 : a0) * rinv[tl] * swf;
            int r = t / WS, cc = t - r*WS;
            int sh = wy*WS + r - WS/2;  if (sh < 0) sh += IMG;
            int sw = wx*WS + cc + WS/2; if (sw >= IMG) sw -= IMG;
            yf[((size_t)(bi*CIN + yc)*IMG + sh)*IMG + sw] = f2b(ov);
        }
    }
}

extern "C" void kernel_launch(void* const* d_in, const int* in_sizes, int n_in,
                              void* d_out, int out_size, void* d_ws, size_t ws_size,
                              hipStream_t stream)
{
    (void)in_sizes; (void)n_in; (void)out_size; (void)ws_size;
    const float* x   = (const float*)d_in[0];
    const float* pw  = (const float*)d_in[1];
    const float* pb  = (const float*)d_in[2];
    const float* gg  = (const float*)d_in[3];
    const float* gb  = (const float*)d_in[4];
    // d_in[5] token_scores: unused (global-token branch is mathematically identity)
    const float* swt = (const float*)d_in[6];
    const float* fw  = (const float*)d_in[7];
    const float* fb  = (const float*)d_in[8];

    float* out  = (float*)d_out;
    float* atn0 = out + 13271040;            // (4608,2,16,16)
    float* atn1 = out + 15630336;            // (1152,4,64,64)
    float* atn2 = out + 34504704;            // (512,6,144,144)

    char* ws = (char*)d_ws;
    bf16*  xp    = (bf16*)ws;                               // 26,542,080 elems
    bf16*  yf    = (bf16*)(ws + 53084160);                  // 13,271,040 elems
    float* stats = (float*)(ws + 53084160 + 26542080);      // 16 floats

    hipMemsetAsync(stats, 0, 64, stream);
    // proj GEMM (MFMA, 3-pass split) + GN partial sums: 6 Mtiles x 576 Ntiles
    k_gemm_mfma<360,180,2,true,float,bf16><<<dim3(3456,1,2), 256, 0, stream>>>(pw, pb, x, xp, stats);
    k_stats<<<1, 64, 0, stream>>>(stats);
    // attention scales: <WS,HE,CHN,SI,SPLIT,RROW,NSC>
    k_attn<4, 2, 30, 0, 1, 1, 16><<<dim3(4608,2,1), 256, 0, stream>>>(xp, stats+8, gg, gb, swt, atn0, yf);
    k_attn<8, 4, 15, 1, 1, 2, 8 ><<<dim3(1152,4,1), 256, 0, stream>>>(xp, stats+8, gg, gb, swt, atn1, yf);
    k_attn<12,6, 10, 2, 2, 2, 8 ><<<dim3(512, 6,2), 256, 0, stream>>>(xp, stats+8, gg, gb, swt, atn2, yf);
    // fuse GEMM (MFMA, 2-pass W split; scale_weights already folded into yf): 3 Mtiles x 576 Ntiles
    k_gemm_mfma<180,180,1,false,bf16,float><<<dim3(1728,1,2), 256, 0, stream>>>(fw, fb, yf, out, nullptr);
}

// Round 3
// 957.320 us; speedup vs baseline: 1.5628x; 1.2973x over previous
//
#include <hip/hip_runtime.h>
#include <hip/hip_bf16.h>
#include <cstdint>

// GMMSA: proj(1x1) -> GroupNorm(2) -> 3x windowed self-attn (q==k) -> fuse(1x1)
// Identity used: attn_g rows == attn rows at gidx  =>  global-token branch is a
// no-op; outputs are exactly (fuse(concat(sw_i * attn_i @ v_i)), attn_0..2).
// I/O dtype: float32 (per reference). Internal xp/yf staged as bf16 in d_ws.
//
// MFMA split-precision (verified R2): proj Y = Wh*Xh + Wh*Xl + Wl*Xh ; fuse Y = (Wh+Wl)*X.
// R3: prep kernel pre-splits/swizzles W into fragment order; GEMM blocks = full-M x 64px,
// waves 2Mx2N with register-resident B-frags; LDS-transpose epilogue (coalesced stores).
// attn: LDS q/v as [c][t] (odd stride), pixel-fast lane indexing everywhere.

typedef __hip_bfloat16 bf16;
typedef __hip_bfloat162 bf162;
typedef __attribute__((ext_vector_type(8))) __bf16 bf16x8;
typedef __attribute__((ext_vector_type(4))) float f32x4;

#define IMG 192
#define PIX (IMG*IMG)   // 36864
#define CIN 180
#define CMID 360

__device__ __forceinline__ float b2f(bf16 v){ return __bfloat162float(v); }
__device__ __forceinline__ bf16 f2b(float v){ return __float2bfloat16(v); }

__device__ __forceinline__ void st2(float* p, float a, float b){
    *reinterpret_cast<float2*>(p) = make_float2(a, b);
}

__device__ __forceinline__ void split2(float x, unsigned short& h, unsigned short& l){
    __bf16 bh = (__bf16)x;
    float fh = (float)bh;
    __bf16 bl = (__bf16)(x - fh);
    h = __builtin_bit_cast(unsigned short, bh);
    l = __builtin_bit_cast(unsigned short, bl);
}

union FragU { unsigned short s[8]; uint32_t u[4]; bf16x8 v; };

__device__ __forceinline__ f32x4 mf(bf16x8 a, bf16x8 b, f32x4 c){
    return __builtin_amdgcn_mfma_f32_16x16x32_bf16(a, b, c, 0, 0, 0);
}

// ---- prep: split W into hi/lo bf16 and store in MFMA A-fragment order ----
// layout: WF[split][mm][s][lane][8]  (lane: am=l&15 -> row mm*16+am, kg=l>>4, k=s*32+kg*8+j)
__global__ void k_prep(const float* __restrict__ pw, const float* __restrict__ fw,
                       bf16* __restrict__ WFp, bf16* __restrict__ WFf)
{
    const int which = blockIdx.y;
    const int MI = which ? 12 : 24;
    const int M  = which ? 180 : 360;
    const float* W = which ? fw : pw;
    bf16* out = which ? WFf : WFp;
    int gid = blockIdx.x*256 + threadIdx.x;
    if (gid >= MI*6*64) return;
    const int l  = gid & 63;
    const int s  = (gid >> 6) % 6;
    const int mm = gid / (6*64);
    const int am = l & 15, kg = l >> 4;
    const int row = mm*16 + am;
    FragU h, lo;
#pragma unroll
    for (int j=0;j<8;j++){
        int k = s*32 + kg*8 + j;
        float x = (row < M && k < 180) ? W[(size_t)row*180 + k] : 0.f;
        unsigned short hh, ll;
        split2(x, hh, ll);
        h.s[j] = hh; lo.s[j] = ll;
    }
    size_t base = (size_t)gid*8;
    *reinterpret_cast<bf16x8*>(out + base) = h.v;
    *reinterpret_cast<bf16x8*>(out + (size_t)MI*6*64*8 + base) = lo.v;
}

// ---- MFMA 1x1-conv GEMM, full-M x 64px per block --------------------------
// 4 waves = 2(M) x 2(N): wave (mw,nw) computes mm = mw*MPW..+MPW-1, px cols nw*32..+31.
// B-frags (X) built once from LDS into registers; A streamed from pre-swizzled WF.
// Epilogue: per-mm LDS transpose -> 1 coalesced dwordx4 store per lane (+GN stats).
template<int MT, int MI, int MPW, bool XF32, bool STATS, typename XT, typename YT>
__global__ __launch_bounds__(256, 2) void k_gemm_mfma(
    const bf16* __restrict__ WF, const float* __restrict__ Bv,
    const XT* __restrict__ X, YT* __restrict__ Y, float* __restrict__ stats)
{
    constexpr int LX = 66;                       // LDS row stride in words
    constexpr int NWORDS = XF32 ? 192*LX : 96*LX;
    __shared__ uint32_t lds[NWORDS];
    __shared__ float red[4][4];

    const int tid = threadIdx.x;
    const int bz  = blockIdx.z;
    const int p0  = blockIdx.x * 64;
    const int w  = tid >> 6, l = tid & 63;
    const int mw = w >> 1,  nw = w & 1;
    const int am = l & 15,  kg = l >> 4;

    // ---- stage X tile (64 px, K padded to 192 with zeros) ----
    if constexpr (XF32) {
        // f32 rows [k][p]; hi/lo split happens at B-frag build
        for (int idx = tid; idx < 192*32; idx += 256){
            int k = idx >> 5, p2 = idx & 31;
            float2 v = make_float2(0.f, 0.f);
            if (k < 180)
                v = *reinterpret_cast<const float2*>(X + ((size_t)(bz*180 + k))*PIX + p0 + 2*p2);
            *reinterpret_cast<float2*>(&lds[k*LX + 2*p2]) = v;
        }
    } else {
        // packed bf16 k-pairs [k2][p]: dword = (k even low, k odd high)
        const unsigned short* Xu = reinterpret_cast<const unsigned short*>(X);
        for (int idx = tid; idx < 96*32; idx += 256){
            int k2 = idx >> 5, p2 = idx & 31;
            uint32_t d0 = 0, d1 = 0;
            if (2*k2 < 180){
                uint32_t a = *reinterpret_cast<const uint32_t*>(Xu + ((size_t)(bz*180 + 2*k2  ))*PIX + p0 + 2*p2);
                uint32_t b = *reinterpret_cast<const uint32_t*>(Xu + ((size_t)(bz*180 + 2*k2+1))*PIX + p0 + 2*p2);
                d0 = (a & 0xFFFFu) | (b << 16);
                d1 = (a >> 16)     | (b & 0xFFFF0000u);
            }
            lds[k2*LX + 2*p2]     = d0;
            lds[k2*LX + 2*p2 + 1] = d1;
        }
    }
    __syncthreads();

    // ---- build register-resident B-frags for this wave's 2 N-subtiles ----
    bf16x8 Bh[6][2], Bl[6][2];
#pragma unroll
    for (int s=0;s<6;s++){
#pragma unroll
        for (int j=0;j<2;j++){
            const int col = (nw*2 + j)*16 + am;
            FragU h;
            if constexpr (XF32) {
                FragU lo;
                const float* lf = reinterpret_cast<const float*>(lds);
#pragma unroll
                for (int j2=0;j2<4;j2++){
                    int k0 = s*32 + kg*8 + 2*j2;
                    float f0 = lf[(k0  )*LX + col];
                    float f1 = lf[(k0+1)*LX + col];
                    unsigned short h0,l0,h1,l1;
                    split2(f0,h0,l0); split2(f1,h1,l1);
                    h.u[j2]  = (uint32_t)h0 | ((uint32_t)h1 << 16);
                    lo.u[j2] = (uint32_t)l0 | ((uint32_t)l1 << 16);
                }
                Bh[s][j] = h.v; Bl[s][j] = lo.v;
            } else {
#pragma unroll
                for (int j2=0;j2<4;j2++)
                    h.u[j2] = lds[(s*16 + kg*4 + j2)*LX + col];
                Bh[s][j] = h.v;
            }
        }
    }
    __syncthreads();   // all waves done reading staged X; lds now reused as scratch

    float* scr = reinterpret_cast<float*>(lds) + w*(16*36);  // per-wave transpose scratch
    float s0=0.f,s1=0.f,q0=0.f,q1=0.f;

    for (int i=0;i<MPW;i++){
        const int mm = mw*MPW + i;
        // A-frags: coalesced 16B/lane from pre-swizzled WF
        bf16x8 Ah[6], Al[6];
#pragma unroll
        for (int s=0;s<6;s++){
            Ah[s] = *reinterpret_cast<const bf16x8*>(WF + (((size_t)(0*MI + mm)*6 + s)*64 + l)*8);
            Al[s] = *reinterpret_cast<const bf16x8*>(WF + (((size_t)(1*MI + mm)*6 + s)*64 + l)*8);
        }
        f32x4 aA[2], aB[2];
#pragma unroll
        for (int j=0;j<2;j++){ aA[j]=(f32x4){0,0,0,0}; aB[j]=(f32x4){0,0,0,0}; }
#pragma unroll
        for (int s=0;s<6;s++){
#pragma unroll
            for (int j=0;j<2;j++){
                f32x4 t = (s&1) ? aB[j] : aA[j];
                t = mf(Ah[s], Bh[s][j], t);
                if constexpr (XF32) {
                    t = mf(Ah[s], Bl[s][j], t);
                    t = mf(Al[s], Bh[s][j], t);
                } else {
                    t = mf(Al[s], Bh[s][j], t);
                }
                if (s&1) aB[j]=t; else aA[j]=t;
            }
        }
        // transpose via per-wave scratch: write D-layout, read row-major
#pragma unroll
        for (int j=0;j<2;j++){
#pragma unroll
            for (int r=0;r<4;r++)
                scr[(kg*4+r)*36 + j*16 + am] = aA[j][r] + aB[j][r];
        }
        asm volatile("s_waitcnt lgkmcnt(0)" ::: "memory");
        const int row = l >> 2, c8 = (l & 3)*8;
        float4 fa = *reinterpret_cast<const float4*>(&scr[row*36 + c8]);
        float4 fb = *reinterpret_cast<const float4*>(&scr[row*36 + c8 + 4]);
        const int o = mm*16 + row;
        if (o < MT){
            const float bb = Bv[o];
            float v[8] = {fa.x+bb, fa.y+bb, fa.z+bb, fa.w+bb,
                          fb.x+bb, fb.y+bb, fb.z+bb, fb.w+bb};
            if (STATS){
                float ls=0.f, lq=0.f;
#pragma unroll
                for (int j=0;j<8;j++){ ls += v[j]; lq = fmaf(v[j], v[j], lq); }
                if (o < 180){ s0 += ls; q0 += lq; } else { s1 += ls; q1 += lq; }
            }
            size_t yi = ((size_t)bz*MT + o)*PIX + p0 + nw*32 + c8;
            if constexpr (sizeof(YT)==2){
                unsigned short u[8];
#pragma unroll
                for (int j=0;j<8;j++) u[j] = __builtin_bit_cast(unsigned short, f2b(v[j]));
                *reinterpret_cast<uint4*>(&Y[yi]) = *reinterpret_cast<uint4*>(u);
            } else {
                *reinterpret_cast<float4*>(&Y[yi])   = make_float4(v[0],v[1],v[2],v[3]);
                *reinterpret_cast<float4*>(&Y[yi+4]) = make_float4(v[4],v[5],v[6],v[7]);
            }
        }
        asm volatile("s_waitcnt lgkmcnt(0)" ::: "memory");  // reads done before next overwrite
    }

    if (STATS){
#pragma unroll
        for (int off=32; off>0; off>>=1){
            s0 += __shfl_down(s0, off); s1 += __shfl_down(s1, off);
            q0 += __shfl_down(q0, off); q1 += __shfl_down(q1, off);
        }
        if (l==0){ red[0][w]=s0; red[1][w]=s1; red[2][w]=q0; red[3][w]=q1; }
        __syncthreads();
        if (tid==0){
            float r0=red[0][0]+red[0][1]+red[0][2]+red[0][3];
            float r1=red[1][0]+red[1][1]+red[1][2]+red[1][3];
            float r2=red[2][0]+red[2][1]+red[2][2]+red[2][3];
            float r3=red[3][0]+red[3][1]+red[3][2]+red[3][3];
            atomicAdd(&stats[(bz*2+0)*2+0], r0);
            atomicAdd(&stats[(bz*2+1)*2+0], r1);
            atomicAdd(&stats[(bz*2+0)*2+1], r2);
            atomicAdd(&stats[(bz*2+1)*2+1], r3);
        }
    }
}

// ---- finalize GN stats ----
__global__ void k_stats(float* stats)
{
    int i = threadIdx.x;
    if (i < 4) {
        const float n = 180.0f*36864.0f;
        float mu  = stats[i*2] / n;
        float var = stats[i*2+1]/n - mu*mu;
        stats[8 + i*2]     = mu;
        stats[8 + i*2 + 1] = rsqrtf(var + 1e-5f);
    }
}

// ---- windowed self-attention (q==k) ---------------------------------------
// LDS q/v as [c][t] with odd stride TP -> conflict-free; pixel index lane-fast
// in load/PV/store loops -> line-local global access (no 442KB lane strides).
template<int WS, int HE, int CHN, int SI, int SPLIT, int RROW, int NSC>
__global__ __launch_bounds__(256) void k_attn(
    const bf16* __restrict__ xp, const float* __restrict__ musig,
    const float* __restrict__ gamma, const float* __restrict__ beta,
    const float* __restrict__ swt,
    float* __restrict__ atn, bf16* __restrict__ yf)
{
    constexpr int T = WS*WS;
    constexpr int NWIN = IMG/WS;
    constexpr int TR = T/SPLIT;
    constexpr int PP = TR/RROW;
    constexpr int SLEN = T/NSC;
    constexpr int ST = TR + 1;
    constexpr int TP = T + 1;         // odd stride: c-strided reads conflict-free
    __shared__ float qs[CHN*TP];
    __shared__ float vs[CHN*TP];
    __shared__ float Sm[T*ST];        // [s][tl]
    __shared__ float rinv[TR];

    const int tid = threadIdx.x;
    const int wid = blockIdx.x;
    const int head = blockIdx.y;
    const int tb = blockIdx.z * TR;
    const int bi = wid / (NWIN*NWIN);
    const int r2 = wid - bi*(NWIN*NWIN);
    const int wy = r2 / NWIN;
    const int wx = r2 - wy*NWIN;

    // load Q/V with GroupNorm applied; rolls folded; t lane-fast
    for (int idx = tid; idx < 2*T*CHN; idx += 256) {
        int qv = idx / (T*CHN);
        int rem = idx - qv*(T*CHN);
        int c = rem / T;
        int t = rem - c*T;
        int chan = SI*120 + qv*60 + c*HE + head;
        int r = t / WS, cc = t - r*WS;
        int sh = wy*WS + r - WS/2;  if (sh < 0) sh += IMG;
        int sw = wx*WS + cc + WS/2; if (sw >= IMG) sw -= IMG;
        float val = b2f(xp[((size_t)(bi*CMID + chan)*IMG + sh)*IMG + sw]);
        int g = (chan >= 180) ? 1 : 0;
        float mu = musig[(bi*2+g)*2+0];
        float rs = musig[(bi*2+g)*2+1];
        float xn = fmaf((val - mu)*rs, gamma[chan], beta[chan]);
        if (qv) vs[c*TP+t] = xn; else qs[c*TP+t] = xn;
    }
    __syncthreads();

    // S[t,s] = (q[t].q[s]) / HE
    constexpr float invHE = 1.0f/(float)HE;
    for (int item = tid; item < PP*NSC; item += 256) {
        int sc = item / PP;
        int p2 = item - sc*PP;
        int tl0 = p2*RROW;
        float qreg[RROW][CHN];
#pragma unroll
        for (int rr=0; rr<RROW; ++rr)
#pragma unroll
            for (int c=0;c<CHN;c++)
                qreg[rr][c] = qs[c*TP + tb + tl0 + rr];
        for (int j=0;j<SLEN;++j) {
            int s = sc*SLEN + j;
            float d[RROW];
#pragma unroll
            for (int rr=0;rr<RROW;++rr) d[rr]=0.f;
#pragma unroll
            for (int c=0;c<CHN;c++){
                float qc = qs[c*TP + s];
#pragma unroll
                for (int rr=0;rr<RROW;++rr)
                    d[rr] = fmaf(qreg[rr][c], qc, d[rr]);
            }
#pragma unroll
            for (int rr=0;rr<RROW;++rr)
                Sm[s*ST + tl0 + rr] = d[rr]*invHE;
        }
    }
    __syncthreads();

    // per-row softmax
    for (int tl = tid; tl < TR; tl += 256) {
        float mx = -1e30f;
        for (int s=0;s<T;s++) mx = fmaxf(mx, Sm[s*ST + tl]);
        float sum = 0.f;
        for (int s=0;s<T;s++){
            float e = __expf(Sm[s*ST + tl] - mx);
            Sm[s*ST + tl] = e;
            sum += e;
        }
        rinv[tl] = 1.0f/sum;
    }
    __syncthreads();

    // write P (== out_attn) — coalesced float2
    {
        size_t abase = ((size_t)wid*HE + head)*(size_t)(T*T) + (size_t)tb*T;
        for (int e2 = tid; e2 < TR*T/2; e2 += 256) {
            int e = e2*2;
            int tl = e / T;
            int s = e - tl*T;
            float ri = rinv[tl];
            st2(atn + abase + e, Sm[s*ST + tl]*ri, Sm[(s+1)*ST + tl]*ri);
        }
    }

    // out[t,c] -> y_fused; t lane-fast (uniform vs reads, line-local stores)
    float swf = swt[SI];
    for (int item = tid; item < CHN*(TR/2); item += 256) {
        int c = item / (TR/2);
        int tp = item - c*(TR/2);
        int tl0 = tp*2;
        float a0=0.f, a1=0.f;
        for (int s=0;s<T;s++){
            float vv = vs[c*TP + s];
            a0 = fmaf(Sm[s*ST + tl0],   vv, a0);
            a1 = fmaf(Sm[s*ST + tl0+1], vv, a1);
        }
        int yc = SI*60 + c*HE + head;
#pragma unroll
        for (int k2=0;k2<2;k2++){
            int tl = tl0 + k2;
            int t = tb + tl;
            float ov = (k2 ? a1 : a0) * rinv[tl] * swf;
            int r = t / WS, cc = t - r*WS;
            int sh = wy*WS + r - WS/2;  if (sh < 0) sh += IMG;
            int sw = wx*WS + cc + WS/2; if (sw >= IMG) sw -= IMG;
            yf[((size_t)(bi*CIN + yc)*IMG + sh)*IMG + sw] = f2b(ov);
        }
    }
}

extern "C" void kernel_launch(void* const* d_in, const int* in_sizes, int n_in,
                              void* d_out, int out_size, void* d_ws, size_t ws_size,
                              hipStream_t stream)
{
    (void)in_sizes; (void)n_in; (void)out_size; (void)ws_size;
    const float* x   = (const float*)d_in[0];
    const float* pw  = (const float*)d_in[1];
    const float* pb  = (const float*)d_in[2];
    const float* gg  = (const float*)d_in[3];
    const float* gb  = (const float*)d_in[4];
    // d_in[5] token_scores: unused (global-token branch is mathematically identity)
    const float* swt = (const float*)d_in[6];
    const float* fw  = (const float*)d_in[7];
    const float* fb  = (const float*)d_in[8];

    float* out  = (float*)d_out;
    float* atn0 = out + 13271040;            // (4608,2,16,16)
    float* atn1 = out + 15630336;            // (1152,4,64,64)
    float* atn2 = out + 34504704;            // (512,6,144,144)

    char* ws = (char*)d_ws;
    bf16*  xp    = (bf16*)ws;                               // 53,084,160 B
    bf16*  yf    = (bf16*)(ws + 53084160);                  // 26,542,080 B
    float* stats = (float*)(ws + 79626240);                 // 64 B
    bf16*  WFp   = (bf16*)(ws + 79626304);                  // 294,912 B (2x24x6x64x8)
    bf16*  WFf   = (bf16*)(ws + 79921216);                  // 147,456 B (2x12x6x64x8)

    hipMemsetAsync(stats, 0, 64, stream);
    k_prep<<<dim3(36,2,1), 256, 0, stream>>>(pw, fw, WFp, WFf);
    // proj GEMM (MFMA, 3-pass split) + GN partial sums
    k_gemm_mfma<360,24,12,true,true,float,bf16><<<dim3(576,1,2), 256, 0, stream>>>(WFp, pb, x, xp, stats);
    k_stats<<<1, 64, 0, stream>>>(stats);
    // attention scales: <WS,HE,CHN,SI,SPLIT,RROW,NSC>
    k_attn<4, 2, 30, 0, 1, 1, 16><<<dim3(4608,2,1), 256, 0, stream>>>(xp, stats+8, gg, gb, swt, atn0, yf);
    k_attn<8, 4, 15, 1, 1, 2, 8 ><<<dim3(1152,4,1), 256, 0, stream>>>(xp, stats+8, gg, gb, swt, atn1, yf);
    k_attn<12,6, 10, 2, 2, 2, 8 ><<<dim3(512, 6,2), 256, 0, stream>>>(xp, stats+8, gg, gb, swt, atn2, yf);
    // fuse GEMM (MFMA, 2-pass W split; scale_weights folded into yf)
    k_gemm_mfma<180,12,6,false,false,bf16,float><<<dim3(576,1,2), 256, 0, stream>>>(WFf, fb, yf, out, nullptr);
}

// Round 4
// 824.785 us; speedup vs baseline: 1.8140x; 1.1607x over previous
//
#include <hip/hip_runtime.h>
#include <hip/hip_bf16.h>
#include <cstdint>

// GMMSA: proj(1x1) -> GroupNorm(2) -> 3x windowed self-attn (q==k) -> fuse(1x1)
// Identity used: attn_g rows == attn rows at gidx  =>  global-token branch is a
// no-op; outputs are exactly (fuse(concat(sw_i * attn_i @ v_i)), attn_0..2).
// I/O dtype: float32 (per reference). Internal xp/yf staged as bf16 in d_ws.
//
// MFMA split-precision (verified R2): proj Y = Wh*Xh + Wh*Xl + Wl*Xh ; fuse Y = (Wh+Wl)*X.
// R4: attn loads vectorized as dword row-runs (windows are contiguous 2*SEG-byte runs);
// attn2 processes both t-halves in one block (Q/V loaded once, HALVES=2);
// softmax 2-lane split; GEMM stages pre-split bf16 planes and stores D-fragments
// directly (no LDS-transpose epilogue, no lgkmcnt drains in the m-loop).

typedef __hip_bfloat16 bf16;
typedef __hip_bfloat162 bf162;
typedef __attribute__((ext_vector_type(8))) __bf16 bf16x8;
typedef __attribute__((ext_vector_type(4))) float f32x4;

#define IMG 192
#define PIX (IMG*IMG)   // 36864
#define CIN 180
#define CMID 360

__device__ __forceinline__ float b2f(bf16 v){ return __bfloat162float(v); }
__device__ __forceinline__ bf16 f2b(float v){ return __float2bfloat16(v); }

__device__ __forceinline__ void st2(float* p, float a, float b){
    *reinterpret_cast<float2*>(p) = make_float2(a, b);
}

__device__ __forceinline__ void split2(float x, unsigned short& h, unsigned short& l){
    __bf16 bh = (__bf16)x;
    float fh = (float)bh;
    __bf16 bl = (__bf16)(x - fh);
    h = __builtin_bit_cast(unsigned short, bh);
    l = __builtin_bit_cast(unsigned short, bl);
}

union FragU { unsigned short s[8]; uint32_t u[4]; bf16x8 v; };

__device__ __forceinline__ f32x4 mf(bf16x8 a, bf16x8 b, f32x4 c){
    return __builtin_amdgcn_mfma_f32_16x16x32_bf16(a, b, c, 0, 0, 0);
}

// ---- prep: split W into hi/lo bf16 and store in MFMA A-fragment order ----
// layout: WF[split][mm][s][lane][8]  (lane: am=l&15 -> row mm*16+am, kg=l>>4, k=s*32+kg*8+j)
__global__ void k_prep(const float* __restrict__ pw, const float* __restrict__ fw,
                       bf16* __restrict__ WFp, bf16* __restrict__ WFf)
{
    const int which = blockIdx.y;
    const int MI = which ? 12 : 24;
    const int M  = which ? 180 : 360;
    const float* W = which ? fw : pw;
    bf16* out = which ? WFf : WFp;
    int gid = blockIdx.x*256 + threadIdx.x;
    if (gid >= MI*6*64) return;
    const int l  = gid & 63;
    const int s  = (gid >> 6) % 6;
    const int mm = gid / (6*64);
    const int am = l & 15, kg = l >> 4;
    const int row = mm*16 + am;
    FragU h, lo;
#pragma unroll
    for (int j=0;j<8;j++){
        int k = s*32 + kg*8 + j;
        float x = (row < M && k < 180) ? W[(size_t)row*180 + k] : 0.f;
        unsigned short hh, ll;
        split2(x, hh, ll);
        h.s[j] = hh; lo.s[j] = ll;
    }
    size_t base = (size_t)gid*8;
    *reinterpret_cast<bf16x8*>(out + base) = h.v;
    *reinterpret_cast<bf16x8*>(out + (size_t)MI*6*64*8 + base) = lo.v;
}

// ---- MFMA 1x1-conv GEMM, full-M x 64px per block --------------------------
// 4 waves = 2(M) x 2(N). LDS holds pre-split bf16 planes [k2][p] (k-pair packed).
// B-frags register-resident; A streamed from pre-swizzled WF; D stored directly
// from accumulators (16-lane 32B runs), GN stats folded in.
template<int MT, int MI, int MPW, int XSPLIT, bool STATS, typename XT, typename YT>
__global__ __launch_bounds__(256, 2) void k_gemm_mfma(
    const bf16* __restrict__ WF, const float* __restrict__ Bv,
    const XT* __restrict__ X, YT* __restrict__ Y, float* __restrict__ stats)
{
    constexpr int LX = 66;                       // LDS row stride in dwords
    __shared__ uint32_t lds[XSPLIT*96*LX];
    __shared__ float red[4][4];

    const int tid = threadIdx.x;
    const int bz  = blockIdx.z;
    const int p0  = blockIdx.x * 64;
    const int w  = tid >> 6, l = tid & 63;
    const int mw = w >> 1,  nw = w & 1;
    const int am = l & 15,  kg = l >> 4;

    // ---- stage X tile (64 px, K padded to 192): packed bf16 k-pairs, split planes
    if constexpr (XSPLIT == 2) {
        // f32 input: split hi/lo during stage (overlaps load latency)
        for (int idx = tid; idx < 96*32; idx += 256){
            int k2 = idx >> 5, p2 = idx & 31;
            uint32_t h0=0,h1=0,lo0=0,lo1=0;
            if (2*k2 < 180){
                float2 a = *reinterpret_cast<const float2*>(X + ((size_t)(bz*180 + 2*k2  ))*PIX + p0 + 2*p2);
                float2 b = *reinterpret_cast<const float2*>(X + ((size_t)(bz*180 + 2*k2+1))*PIX + p0 + 2*p2);
                unsigned short ha,la,hb,lb;
                split2(a.x,ha,la); split2(b.x,hb,lb);
                h0  = (uint32_t)ha | ((uint32_t)hb << 16);
                lo0 = (uint32_t)la | ((uint32_t)lb << 16);
                split2(a.y,ha,la); split2(b.y,hb,lb);
                h1  = (uint32_t)ha | ((uint32_t)hb << 16);
                lo1 = (uint32_t)la | ((uint32_t)lb << 16);
            }
            lds[k2*LX + 2*p2]           = h0;
            lds[k2*LX + 2*p2 + 1]       = h1;
            lds[96*LX + k2*LX + 2*p2]   = lo0;
            lds[96*LX + k2*LX + 2*p2+1] = lo1;
        }
    } else {
        // bf16 input: repack rows into k-pair dwords
        const unsigned short* Xu = reinterpret_cast<const unsigned short*>(X);
        for (int idx = tid; idx < 96*32; idx += 256){
            int k2 = idx >> 5, p2 = idx & 31;
            uint32_t d0 = 0, d1 = 0;
            if (2*k2 < 180){
                uint32_t a = *reinterpret_cast<const uint32_t*>(Xu + ((size_t)(bz*180 + 2*k2  ))*PIX + p0 + 2*p2);
                uint32_t b = *reinterpret_cast<const uint32_t*>(Xu + ((size_t)(bz*180 + 2*k2+1))*PIX + p0 + 2*p2);
                d0 = (a & 0xFFFFu) | (b << 16);
                d1 = (a >> 16)     | (b & 0xFFFF0000u);
            }
            lds[k2*LX + 2*p2]     = d0;
            lds[k2*LX + 2*p2 + 1] = d1;
        }
    }
    __syncthreads();

    // ---- build register-resident B-frags for this wave's 2 N-subtiles ----
    bf16x8 Bh[6][2], Bl[6][2];
#pragma unroll
    for (int s=0;s<6;s++){
#pragma unroll
        for (int j=0;j<2;j++){
            const int col = (nw*2 + j)*16 + am;
            FragU h;
#pragma unroll
            for (int j2=0;j2<4;j2++)
                h.u[j2] = lds[(s*16 + kg*4 + j2)*LX + col];
            Bh[s][j] = h.v;
            if constexpr (XSPLIT == 2) {
                FragU lo;
#pragma unroll
                for (int j2=0;j2<4;j2++)
                    lo.u[j2] = lds[96*LX + (s*16 + kg*4 + j2)*LX + col];
                Bl[s][j] = lo.v;
            }
        }
    }

    float s0=0.f,s1=0.f,q0=0.f,q1=0.f;

    for (int i=0;i<MPW;i++){
        const int mm = mw*MPW + i;
        // A-frags: coalesced 16B/lane from pre-swizzled WF
        bf16x8 Ah[6], Al[6];
#pragma unroll
        for (int s=0;s<6;s++){
            Ah[s] = *reinterpret_cast<const bf16x8*>(WF + (((size_t)(0*MI + mm)*6 + s)*64 + l)*8);
            Al[s] = *reinterpret_cast<const bf16x8*>(WF + (((size_t)(1*MI + mm)*6 + s)*64 + l)*8);
        }
        f32x4 aA[2], aB[2];
#pragma unroll
        for (int j=0;j<2;j++){ aA[j]=(f32x4){0,0,0,0}; aB[j]=(f32x4){0,0,0,0}; }
#pragma unroll
        for (int s=0;s<6;s++){
#pragma unroll
            for (int j=0;j<2;j++){
                f32x4 t = (s&1) ? aB[j] : aA[j];
                t = mf(Ah[s], Bh[s][j], t);
                if constexpr (XSPLIT == 2) {
                    t = mf(Ah[s], Bl[s][j], t);
                    t = mf(Al[s], Bh[s][j], t);
                } else {
                    t = mf(Al[s], Bh[s][j], t);
                }
                if (s&1) aB[j]=t; else aA[j]=t;
            }
        }
        // direct D-fragment store: row o = mm*16+kg*4+r, col p0+(nw*2+j)*16+am
        const int orow0 = mm*16 + kg*4;
#pragma unroll
        for (int r=0;r<4;r++){
            const int o = orow0 + r;
            if (o < MT){
                const float bb = Bv[o];
#pragma unroll
                for (int j=0;j<2;j++){
                    float v = aA[j][r] + aB[j][r] + bb;
                    size_t yi = ((size_t)bz*MT + o)*PIX + p0 + (nw*2+j)*16 + am;
                    if constexpr (sizeof(YT)==2) Y[yi] = f2b(v); else Y[yi] = v;
                    if (STATS){
                        if (o < 180){ s0 += v; q0 = fmaf(v,v,q0); }
                        else        { s1 += v; q1 = fmaf(v,v,q1); }
                    }
                }
            }
        }
    }

    if (STATS){
#pragma unroll
        for (int off=32; off>0; off>>=1){
            s0 += __shfl_down(s0, off); s1 += __shfl_down(s1, off);
            q0 += __shfl_down(q0, off); q1 += __shfl_down(q1, off);
        }
        if (l==0){ red[0][w]=s0; red[1][w]=s1; red[2][w]=q0; red[3][w]=q1; }
        __syncthreads();
        if (tid==0){
            float r0=red[0][0]+red[0][1]+red[0][2]+red[0][3];
            float r1=red[1][0]+red[1][1]+red[1][2]+red[1][3];
            float r2=red[2][0]+red[2][1]+red[2][2]+red[2][3];
            float r3=red[3][0]+red[3][1]+red[3][2]+red[3][3];
            atomicAdd(&stats[(bz*2+0)*2+0], r0);
            atomicAdd(&stats[(bz*2+1)*2+0], r1);
            atomicAdd(&stats[(bz*2+0)*2+1], r2);
            atomicAdd(&stats[(bz*2+1)*2+1], r3);
        }
    }
}

// ---- finalize GN stats ----
__global__ void k_stats(float* stats)
{
    int i = threadIdx.x;
    if (i < 4) {
        const float n = 180.0f*36864.0f;
        float mu  = stats[i*2] / n;
        float var = stats[i*2+1]/n - mu*mu;
        stats[8 + i*2]     = mu;
        stats[8 + i*2 + 1] = rsqrtf(var + 1e-5f);
    }
}

// ---- windowed self-attention (q==k) ---------------------------------------
// One block per (window, head). Q/V loaded ONCE as dword row-runs (24B-contig
// after roll), GN applied, stored [c][t] odd-stride. HALVES t-halves processed
// sequentially reusing Sm (attn2: halves the gather traffic vs SPLIT blocks).
template<int WS, int HE, int CHN, int SI, int HALVES, int RROW, int NSC>
__global__ __launch_bounds__(256) void k_attn(
    const bf16* __restrict__ xp, const float* __restrict__ musig,
    const float* __restrict__ gamma, const float* __restrict__ beta,
    const float* __restrict__ swt,
    float* __restrict__ atn, bf16* __restrict__ yf)
{
    constexpr int T = WS*WS;
    constexpr int NWIN = IMG/WS;
    constexpr int TR = T/HALVES;      // rows of S per pass
    constexpr int PP = TR/RROW;
    constexpr int SLEN = T/NSC;
    constexpr int ST = TR + 1;
    constexpr int TP = T + 1;         // odd stride: c-strided reads conflict-free
    constexpr int SEG = WS/2;         // dwords per window row-run
    __shared__ float qs[CHN*TP];
    __shared__ float vs[CHN*TP];
    __shared__ float Sm[T*ST];        // [s][tl]
    __shared__ float rinv[TR];

    const int tid = threadIdx.x;
    const int wid = blockIdx.x;
    const int head = blockIdx.y;
    const int bi = wid / (NWIN*NWIN);
    const int r2 = wid - bi*(NWIN*NWIN);
    const int wy = r2 / NWIN;
    const int wx = r2 - wy*NWIN;

    // ---- load Q/V once: dword (2px) row-runs, GN applied, rolls folded ----
    const uint32_t* xpu = reinterpret_cast<const uint32_t*>(xp);
    for (int it = tid; it < 2*CHN*WS*SEG; it += 256) {
        int seg  = it % SEG;
        int tmp  = it / SEG;
        int r    = tmp % WS;
        int tmp2 = tmp / WS;
        int c    = tmp2 % CHN;
        int qv   = tmp2 / CHN;
        int chan = SI*120 + qv*60 + c*HE + head;
        int sh = wy*WS + r - WS/2;      if (sh < 0)    sh += IMG;
        int sw0 = wx*WS + 2*seg + WS/2; if (sw0 >= IMG) sw0 -= IMG;
        uint32_t d = xpu[((size_t)(bi*CMID + chan)*IMG + sh)*(IMG/2) + (sw0>>1)];
        float f0 = __uint_as_float(d << 16);
        float f1 = __uint_as_float(d & 0xffff0000u);
        int g = (chan >= 180) ? 1 : 0;
        float mu = musig[(bi*2+g)*2+0];
        float rs = musig[(bi*2+g)*2+1];
        float ga = gamma[chan], be = beta[chan];
        float x0 = fmaf((f0 - mu)*rs, ga, be);
        float x1 = fmaf((f1 - mu)*rs, ga, be);
        int t = r*WS + 2*seg;
        float* dst = qv ? vs : qs;
        dst[c*TP + t]     = x0;
        dst[c*TP + t + 1] = x1;
    }
    __syncthreads();

    constexpr float invHE = 1.0f/(float)HE;
    const float swf = swt[SI];

    for (int ph = 0; ph < HALVES; ++ph) {
        const int tb = ph*TR;

        // ---- S[t,s] = (q[t].q[s]) / HE for t in [tb, tb+TR) ----
        for (int item = tid; item < PP*NSC; item += 256) {
            int sc = item / PP;
            int p2 = item - sc*PP;
            int tl0 = p2*RROW;
            float qreg[RROW][CHN];
#pragma unroll
            for (int rr=0; rr<RROW; ++rr)
#pragma unroll
                for (int c=0;c<CHN;c++)
                    qreg[rr][c] = qs[c*TP + tb + tl0 + rr];
            for (int j=0;j<SLEN;++j) {
                int s = sc*SLEN + j;
                float d[RROW];
#pragma unroll
                for (int rr=0;rr<RROW;++rr) d[rr]=0.f;
#pragma unroll
                for (int c=0;c<CHN;c++){
                    float qc = qs[c*TP + s];
#pragma unroll
                    for (int rr=0;rr<RROW;++rr)
                        d[rr] = fmaf(qreg[rr][c], qc, d[rr]);
                }
#pragma unroll
                for (int rr=0;rr<RROW;++rr)
                    Sm[s*ST + tl0 + rr] = d[rr]*invHE;
            }
        }
        __syncthreads();

        // ---- per-row softmax, 2 lanes per row (s-range split) ----
        for (int pr = tid; pr < 2*TR; pr += 256) {
            int tl = pr >> 1, hf = pr & 1;
            int sBeg = hf*(T/2);
            float mx = -1e30f;
            for (int s=sBeg; s<sBeg+T/2; ++s) mx = fmaxf(mx, Sm[s*ST + tl]);
            mx = fmaxf(mx, __shfl_xor(mx, 1));
            float sum = 0.f;
            for (int s=sBeg; s<sBeg+T/2; ++s){
                float e = __expf(Sm[s*ST + tl] - mx);
                Sm[s*ST + tl] = e;
                sum += e;
            }
            sum += __shfl_xor(sum, 1);
            if (!hf) rinv[tl] = 1.0f/sum;
        }
        __syncthreads();

        // ---- write P (== out_attn) — coalesced float2 ----
        {
            size_t abase = ((size_t)wid*HE + head)*(size_t)(T*T) + (size_t)tb*T;
            for (int e2 = tid; e2 < TR*T/2; e2 += 256) {
                int e = e2*2;
                int tl = e / T;
                int s = e - tl*T;
                float ri = rinv[tl];
                st2(atn + abase + e, Sm[s*ST + tl]*ri, Sm[(s+1)*ST + tl]*ri);
            }
        }

        // ---- out[t,c] -> y_fused (t lane-fast: broadcast vs reads) ----
        for (int item = tid; item < CHN*(TR/2); item += 256) {
            int c = item / (TR/2);
            int tp = item - c*(TR/2);
            int tl0 = tp*2;
            float a0=0.f, a1=0.f;
            for (int s=0;s<T;s++){
                float vv = vs[c*TP + s];
                a0 = fmaf(Sm[s*ST + tl0],   vv, a0);
                a1 = fmaf(Sm[s*ST + tl0+1], vv, a1);
            }
            int yc = SI*60 + c*HE + head;
#pragma unroll
            for (int k2=0;k2<2;k2++){
                int tl = tl0 + k2;
                int t = tb + tl;
                float ov = (k2 ? a1 : a0) * rinv[tl] * swf;
                int r = t / WS, cc = t - r*WS;
                int sh = wy*WS + r - WS/2;  if (sh < 0) sh += IMG;
                int sw = wx*WS + cc + WS/2; if (sw >= IMG) sw -= IMG;
                yf[((size_t)(bi*CIN + yc)*IMG + sh)*IMG + sw] = f2b(ov);
            }
        }
        if (HALVES > 1) __syncthreads();   // Sm/rinv reused next pass
    }
}

extern "C" void kernel_launch(void* const* d_in, const int* in_sizes, int n_in,
                              void* d_out, int out_size, void* d_ws, size_t ws_size,
                              hipStream_t stream)
{
    (void)in_sizes; (void)n_in; (void)out_size; (void)ws_size;
    const float* x   = (const float*)d_in[0];
    const float* pw  = (const float*)d_in[1];
    const float* pb  = (const float*)d_in[2];
    const float* gg  = (const float*)d_in[3];
    const float* gb  = (const float*)d_in[4];
    // d_in[5] token_scores: unused (global-token branch is mathematically identity)
    const float* swt = (const float*)d_in[6];
    const float* fw  = (const float*)d_in[7];
    const float* fb  = (const float*)d_in[8];

    float* out  = (float*)d_out;
    float* atn0 = out + 13271040;            // (4608,2,16,16)
    float* atn1 = out + 15630336;            // (1152,4,64,64)
    float* atn2 = out + 34504704;            // (512,6,144,144)

    char* ws = (char*)d_ws;
    bf16*  xp    = (bf16*)ws;                               // 53,084,160 B
    bf16*  yf    = (bf16*)(ws + 53084160);                  // 26,542,080 B
    float* stats = (float*)(ws + 79626240);                 // 64 B
    bf16*  WFp   = (bf16*)(ws + 79626304);                  // 294,912 B (2x24x6x64x8)
    bf16*  WFf   = (bf16*)(ws + 79921216);                  // 147,456 B (2x12x6x64x8)

    hipMemsetAsync(stats, 0, 64, stream);
    k_prep<<<dim3(36,2,1), 256, 0, stream>>>(pw, fw, WFp, WFf);
    // proj GEMM (MFMA, 3-pass split) + GN partial sums
    k_gemm_mfma<360,24,12,2,true,float,bf16><<<dim3(576,1,2), 256, 0, stream>>>(WFp, pb, x, xp, stats);
    k_stats<<<1, 64, 0, stream>>>(stats);
    // attention scales: <WS,HE,CHN,SI,HALVES,RROW,NSC>
    k_attn<4, 2, 30, 0, 1, 1, 16><<<dim3(4608,2,1), 256, 0, stream>>>(xp, stats+8, gg, gb, swt, atn0, yf);
    k_attn<8, 4, 15, 1, 1, 2, 8 ><<<dim3(1152,4,1), 256, 0, stream>>>(xp, stats+8, gg, gb, swt, atn1, yf);
    k_attn<12,6, 10, 2, 2, 2, 8 ><<<dim3(512, 6,1), 256, 0, stream>>>(xp, stats+8, gg, gb, swt, atn2, yf);
    // fuse GEMM (MFMA, 2-pass W split; scale_weights folded into yf)
    k_gemm_mfma<180,12,6,1,false,bf16,float><<<dim3(576,1,2), 256, 0, stream>>>(WFf, fb, yf, out, nullptr);
}